// Round 2
// baseline (1641.051 us; speedup 1.0000x reference)
//
#include <hip/hip_runtime.h>
#include <math.h>

#define NNODES (128*2048)
#define NEDGES (NNODES*8)
#define NPG 2048
#define NGRAPH 128
#define KSEL1 1639
#define KSEL2 1312

// y = x @ Wrel ; agg = x @ Wroot + b  (seed for scatter)  x:[N,64]
__global__ __launch_bounds__(256) void k_gemm64(
    const float* __restrict__ x, const float* __restrict__ Wrel,
    const float* __restrict__ Wroot, const float* __restrict__ b,
    float* __restrict__ y, float* __restrict__ agg)
{
    __shared__ float wR[64*32];
    __shared__ float wT[64*32];
    __shared__ float bb[32];
    int t = threadIdx.x;
    for (int i = t; i < 64*32; i += 256) { wR[i] = Wrel[i]; wT[i] = Wroot[i]; }
    if (t < 32) bb[t] = b[t];
    __syncthreads();
    size_t node = (size_t)blockIdx.x * 256 + t;
    const float4* xr = (const float4*)(x + node*64);
    float aR[32], aT[32];
    #pragma unroll
    for (int j=0;j<32;++j){aR[j]=0.f;aT[j]=0.f;}
    for (int k4 = 0; k4 < 16; ++k4) {
        float4 xv = xr[k4];
        float xs[4] = {xv.x, xv.y, xv.z, xv.w};
        #pragma unroll
        for (int q=0;q<4;++q) {
            int k = k4*4+q;
            #pragma unroll
            for (int j=0;j<32;++j) {
                aR[j] = fmaf(xs[q], wR[k*32+j], aR[j]);
                aT[j] = fmaf(xs[q], wT[k*32+j], aT[j]);
            }
        }
    }
    float4* yr = (float4*)(y + node*32);
    float4* ar = (float4*)(agg + node*32);
    #pragma unroll
    for (int j4=0;j4<8;++j4) {
        yr[j4] = make_float4(aR[4*j4],aR[4*j4+1],aR[4*j4+2],aR[4*j4+3]);
        ar[j4] = make_float4(aT[4*j4]+bb[4*j4],aT[4*j4+1]+bb[4*j4+1],
                             aT[4*j4+2]+bb[4*j4+2],aT[4*j4+3]+bb[4*j4+3]);
    }
}

// In-place conv2 front-end: reads xagg row (=hp), writes y = hp@Wrel and
// overwrites xagg row with seed = hp@Wroot + b. Per-thread own-row only.
__global__ __launch_bounds__(256) void k_gemm32(
    float* __restrict__ xagg, const float* __restrict__ Wrel,
    const float* __restrict__ Wroot, const float* __restrict__ b,
    float* __restrict__ y)
{
    __shared__ float wR[32*32];
    __shared__ float wT[32*32];
    __shared__ float bb[32];
    int t = threadIdx.x;
    for (int i = t; i < 32*32; i += 256) { wR[i] = Wrel[i]; wT[i] = Wroot[i]; }
    if (t < 32) bb[t] = b[t];
    __syncthreads();
    size_t node = (size_t)blockIdx.x * 256 + t;
    float4* xr = (float4*)(xagg + node*32);
    float xs[32];
    #pragma unroll
    for (int k4=0;k4<8;++k4) {
        float4 xv = xr[k4];
        xs[4*k4]=xv.x; xs[4*k4+1]=xv.y; xs[4*k4+2]=xv.z; xs[4*k4+3]=xv.w;
    }
    float aR[32], aT[32];
    #pragma unroll
    for (int j=0;j<32;++j){aR[j]=0.f;aT[j]=0.f;}
    #pragma unroll
    for (int k=0;k<32;++k) {
        #pragma unroll
        for (int j=0;j<32;++j) {
            aR[j] = fmaf(xs[k], wR[k*32+j], aR[j]);
            aT[j] = fmaf(xs[k], wT[k*32+j], aT[j]);
        }
    }
    float4* yr = (float4*)(y + node*32);
    #pragma unroll
    for (int j4=0;j4<8;++j4) {
        yr[j4] = make_float4(aR[4*j4],aR[4*j4+1],aR[4*j4+2],aR[4*j4+3]);
        xr[j4] = make_float4(aT[4*j4]+bb[4*j4],aT[4*j4+1]+bb[4*j4+1],
                             aT[4*j4+2]+bb[4*j4+2],aT[4*j4+3]+bb[4*j4+3]);
    }
}

// agg[dst] += y[src] * ew  (8 threads per edge, 4 floats each); int32 indices
__global__ __launch_bounds__(256) void k_scatter(
    const int* __restrict__ src, const int* __restrict__ dst,
    const float* __restrict__ ew, const float* __restrict__ y,
    const int* __restrict__ mask, float* __restrict__ agg)
{
    size_t tid = (size_t)blockIdx.x * 256 + threadIdx.x;
    size_t e = tid >> 3;
    int q = (int)(tid & 7);
    int s = src[e], d = dst[e];
    if (mask && !(mask[s] && mask[d])) return;
    float w = ew[e];
    float4 v = *(const float4*)(y + (size_t)s*32 + (size_t)q*4);
    float* a = agg + (size_t)d*32 + (size_t)q*4;
    atomicAdd(a+0, v.x*w);
    atomicAdd(a+1, v.y*w);
    atomicAdd(a+2, v.z*w);
    atomicAdd(a+3, v.w*w);
}

// h = relu(agg) in place; s = (h . pw)/||pw||  (or -inf if masked out)
__global__ __launch_bounds__(256) void k_node(
    float* __restrict__ hagg, const float* __restrict__ pw,
    const int* __restrict__ mask, float* __restrict__ s)
{
    __shared__ float ww[32];
    __shared__ float nrm;
    int t = threadIdx.x;
    if (t < 32) ww[t] = pw[t];
    __syncthreads();
    if (t == 0) {
        float ns = 0.f;
        for (int j=0;j<32;++j) ns += ww[j]*ww[j];
        nrm = sqrtf(ns);
    }
    __syncthreads();
    size_t node = (size_t)blockIdx.x * 256 + t;
    float4* hr = (float4*)(hagg + node*32);
    float dot = 0.f;
    #pragma unroll
    for (int j4=0;j4<8;++j4) {
        float4 a = hr[j4];
        float4 hv;
        hv.x = fmaxf(a.x, 0.f);
        hv.y = fmaxf(a.y, 0.f);
        hv.z = fmaxf(a.z, 0.f);
        hv.w = fmaxf(a.w, 0.f);
        dot += hv.x*ww[4*j4+0] + hv.y*ww[4*j4+1] + hv.z*ww[4*j4+2] + hv.w*ww[4*j4+3];
        hr[j4] = hv;
    }
    bool valid = mask ? (mask[node] != 0) : true;
    s[node] = valid ? (dot / nrm) : -INFINITY;
}

// Per-graph: exact top-ksel on s (radix select, index-stable ties),
// hp = h * tanh(s) (zeros elsewhere, optional), mask_out (optional),
// xout[g] = concat(masked max, masked sum/ksel)
__global__ __launch_bounds__(256) void k_pool(
    const float* __restrict__ s, float* __restrict__ h,
    int write_hp, int* __restrict__ mask_out,
    float* __restrict__ xout, int ksel)
{
    __shared__ unsigned keys[NPG];
    __shared__ unsigned hist[256];
    __shared__ unsigned scanb[256];
    __shared__ unsigned char flag[NPG];
    __shared__ unsigned sh_bin, sh_krem;
    __shared__ float red[4*64];
    int t = threadIdx.x;
    int g = blockIdx.x;
    const float* sg = s + (size_t)g * NPG;
    for (int i = t; i < NPG; i += 256) {
        unsigned u = __float_as_uint(sg[i]);
        keys[i] = (u & 0x80000000u) ? ~u : (u | 0x80000000u);
    }
    __syncthreads();
    unsigned prefix = 0u;
    unsigned krem = (unsigned)ksel;
    for (int level = 0; level < 4; ++level) {
        int shift = 24 - 8*level;
        hist[t] = 0u;
        __syncthreads();
        unsigned pmask = level ? (0xFFFFFFFFu << (shift + 8)) : 0u;
        for (int i = t; i < NPG; i += 256) {
            unsigned key = keys[i];
            if ((key & pmask) == prefix)
                atomicAdd(&hist[(key >> shift) & 0xFFu], 1u);
        }
        __syncthreads();
        scanb[t] = hist[255 - t];
        __syncthreads();
        for (int off = 1; off < 256; off <<= 1) {
            unsigned add = (t >= off) ? scanb[t - off] : 0u;
            __syncthreads();
            scanb[t] += add;
            __syncthreads();
        }
        unsigned incl = scanb[t];
        unsigned excl = t ? scanb[t-1] : 0u;
        if (incl >= krem && excl < krem) {
            sh_bin = (unsigned)(255 - t);
            sh_krem = krem - excl;
        }
        __syncthreads();
        prefix |= (sh_bin << shift);
        krem = sh_krem;
        __syncthreads();
    }
    unsigned T = prefix;
    unsigned ties = krem;
    // stable tie selection in index order
    int base = t * 8;
    unsigned ceq = 0;
    #pragma unroll
    for (int i=0;i<8;++i) ceq += (keys[base+i] == T) ? 1u : 0u;
    scanb[t] = ceq;
    __syncthreads();
    for (int off = 1; off < 256; off <<= 1) {
        unsigned add = (t >= off) ? scanb[t - off] : 0u;
        __syncthreads();
        scanb[t] += add;
        __syncthreads();
    }
    unsigned run = scanb[t] - ceq;   // exclusive prefix of ties
    #pragma unroll
    for (int i=0;i<8;++i) {
        unsigned key = keys[base+i];
        unsigned char f;
        if (key > T) f = 1;
        else if (key == T) { f = (run < ties) ? 1 : 0; run++; }
        else f = 0;
        flag[base+i] = f;
    }
    __syncthreads();

    float mx[32], sm[32];
    #pragma unroll
    for (int j=0;j<32;++j){ mx[j]=-INFINITY; sm[j]=0.f; }
    float* hg = h + (size_t)g * NPG * 32;
    for (int i = t; i < NPG; i += 256) {
        bool sel = flag[i] != 0;
        float ts = sel ? tanhf(sg[i]) : 0.f;
        float4* hr = (float4*)(hg + (size_t)i*32);
        #pragma unroll
        for (int j4=0;j4<8;++j4) {
            float4 hv = hr[j4];
            float4 v = make_float4(hv.x*ts, hv.y*ts, hv.z*ts, hv.w*ts);
            if (write_hp) hr[j4] = v;
            if (sel) {
                mx[4*j4+0] = fmaxf(mx[4*j4+0], v.x); sm[4*j4+0] += v.x;
                mx[4*j4+1] = fmaxf(mx[4*j4+1], v.y); sm[4*j4+1] += v.y;
                mx[4*j4+2] = fmaxf(mx[4*j4+2], v.z); sm[4*j4+2] += v.z;
                mx[4*j4+3] = fmaxf(mx[4*j4+3], v.w); sm[4*j4+3] += v.w;
            }
        }
        if (mask_out) mask_out[(size_t)g*NPG + i] = sel ? 1 : 0;
    }
    // wave reduce (64 lanes), then cross-wave via LDS
    #pragma unroll
    for (int j=0;j<32;++j) {
        for (int off=32; off; off>>=1) {
            mx[j] = fmaxf(mx[j], __shfl_xor(mx[j], off));
            sm[j] += __shfl_xor(sm[j], off);
        }
    }
    int wave = t >> 6, lane = t & 63;
    if (lane == 0) {
        #pragma unroll
        for (int j=0;j<32;++j) { red[wave*64 + j] = mx[j]; red[wave*64 + 32 + j] = sm[j]; }
    }
    __syncthreads();
    if (t < 32) {
        float m = red[t], ss = red[32 + t];
        #pragma unroll
        for (int w=1; w<4; ++w) { m = fmaxf(m, red[w*64 + t]); ss += red[w*64 + 32 + t]; }
        xout[(size_t)g*64 + t] = m;
        xout[(size_t)g*64 + 32 + t] = ss / (float)ksel;
    }
}

__global__ __launch_bounds__(128) void k_readout(
    const float* __restrict__ x1, const float* __restrict__ x2,
    const float* __restrict__ l1W, const float* __restrict__ l1b,
    const float* __restrict__ l2W, const float* __restrict__ l2b,
    const float* __restrict__ l3W, const float* __restrict__ l3b,
    float* __restrict__ out)
{
    int g = threadIdx.x;
    float z[64];
    #pragma unroll
    for (int i=0;i<64;++i) z[i] = x1[g*64+i] + x2[g*64+i];
    float a1[32];
    for (int j=0;j<32;++j) {
        float acc = l1b[j];
        #pragma unroll
        for (int i=0;i<64;++i) acc = fmaf(z[i], l1W[i*32+j], acc);
        a1[j] = fmaxf(acc, 0.f);
    }
    float a2[16];
    for (int j=0;j<16;++j) {
        float acc = l2b[j];
        #pragma unroll
        for (int i=0;i<32;++i) acc = fmaf(a1[i], l2W[i*16+j], acc);
        a2[j] = fmaxf(acc, 0.f);
    }
    float o0 = l3b[0], o1 = l3b[1];
    #pragma unroll
    for (int i=0;i<16;++i) { o0 = fmaf(a2[i], l3W[i*2+0], o0); o1 = fmaf(a2[i], l3W[i*2+1], o1); }
    float m = fmaxf(o0, o1);
    float lse = m + logf(expf(o0-m) + expf(o1-m));
    out[g*2+0] = o0 - lse;
    out[g*2+1] = o1 - lse;
}

extern "C" void kernel_launch(void* const* d_in, const int* in_sizes, int n_in,
                              void* d_out, int out_size, void* d_ws, size_t ws_size,
                              hipStream_t stream)
{
    const float* x      = (const float*)d_in[0];
    const int*   ei     = (const int*)d_in[1];   // int32! (JAX x64 disabled)
    const float* eattr  = (const float*)d_in[2];
    const float* W1rel  = (const float*)d_in[4];
    const float* b1     = (const float*)d_in[5];
    const float* W1root = (const float*)d_in[6];
    const float* p1w    = (const float*)d_in[7];
    const float* W2rel  = (const float*)d_in[8];
    const float* b2     = (const float*)d_in[9];
    const float* W2root = (const float*)d_in[10];
    const float* p2w    = (const float*)d_in[11];
    const float* l1W    = (const float*)d_in[12];
    const float* l1b    = (const float*)d_in[13];
    const float* l2W    = (const float*)d_in[14];
    const float* l2b    = (const float*)d_in[15];
    const float* l3W    = (const float*)d_in[16];
    const float* l3b    = (const float*)d_in[17];
    const int* srcp = ei;
    const int* dstp = ei + NEDGES;

    float* ws   = (float*)d_ws;
    float* y    = ws;                              // [NNODES,32]
    float* aggh = y    + (size_t)NNODES*32;        // [NNODES,32] seed/agg/h/hp
    float* s1   = aggh + (size_t)NNODES*32;        // [NNODES]
    int*   mask = (int*)(s1 + NNODES);             // [NNODES]
    float* x1   = (float*)(mask + NNODES);         // [128,64]
    float* x2   = x1 + NGRAPH*64;                  // [128,64]
    float* out  = (float*)d_out;

    dim3 b256(256);
    // ---- conv1 ----
    k_gemm64<<<NNODES/256, b256, 0, stream>>>(x, W1rel, W1root, b1, y, aggh);
    k_scatter<<<(NEDGES*8)/256, b256, 0, stream>>>(srcp, dstp, eattr, y, nullptr, aggh);
    k_node<<<NNODES/256, b256, 0, stream>>>(aggh, p1w, nullptr, s1);
    // ---- pool1 (hp in place, mask, x1) ----
    k_pool<<<NGRAPH, b256, 0, stream>>>(s1, aggh, 1, mask, x1, KSEL1);
    // ---- conv2 (in-place seed) ----
    k_gemm32<<<NNODES/256, b256, 0, stream>>>(aggh, W2rel, W2root, b2, y);
    k_scatter<<<(NEDGES*8)/256, b256, 0, stream>>>(srcp, dstp, eattr, y, mask, aggh);
    k_node<<<NNODES/256, b256, 0, stream>>>(aggh, p2w, mask, s1);
    // ---- pool2 (x2 only) ----
    k_pool<<<NGRAPH, b256, 0, stream>>>(s1, aggh, 0, nullptr, x2, KSEL2);
    // ---- readout MLP ----
    k_readout<<<1, 128, 0, stream>>>(x1, x2, l1W, l1b, l2W, l2b, l3W, l3b, out);
}

// Round 3
// 507.578 us; speedup vs baseline: 3.2331x; 3.2331x over previous
//
#include <hip/hip_runtime.h>
#include <math.h>

#define NNODES (128*2048)
#define NEDGES (NNODES*8)
#define NPG 2048
#define NGRAPH 128
#define KSEL1 1639
#define KSEL2 1312

__global__ __launch_bounds__(256) void k_zeroi(int4* __restrict__ p) {
    p[blockIdx.x * 256 + threadIdx.x] = make_int4(0,0,0,0);
}

// ---------- CSR build (by dst) ----------
__global__ __launch_bounds__(256) void k_hist(const int* __restrict__ dst,
                                              int* __restrict__ counts) {
    int e = blockIdx.x * 256 + threadIdx.x;
    atomicAdd(&counts[dst[e]], 1);
}

// exclusive scan of 262144 ints: 256 blocks x 1024 elems
__global__ __launch_bounds__(256) void k_scan1(const int* __restrict__ cnt,
                                               int* __restrict__ out,
                                               int* __restrict__ blocksum) {
    __shared__ int sb[256];
    int t = threadIdx.x;
    int base = blockIdx.x * 1024 + t * 4;
    int4 v = *(const int4*)(cnt + base);
    int tsum = v.x + v.y + v.z + v.w;
    sb[t] = tsum;
    __syncthreads();
    for (int off = 1; off < 256; off <<= 1) {
        int add = (t >= off) ? sb[t - off] : 0;
        __syncthreads();
        sb[t] += add;
        __syncthreads();
    }
    int excl = sb[t] - tsum;
    int4 o;
    o.x = excl; o.y = excl + v.x; o.z = o.y + v.y; o.w = o.z + v.z;
    *(int4*)(out + base) = o;
    if (t == 255) blocksum[blockIdx.x] = sb[255];
}

__global__ __launch_bounds__(256) void k_scan2(const int* __restrict__ blocksum,
                                               int* __restrict__ blockbase) {
    __shared__ int sb[256];
    int t = threadIdx.x;
    int v = blocksum[t];
    sb[t] = v;
    __syncthreads();
    for (int off = 1; off < 256; off <<= 1) {
        int add = (t >= off) ? sb[t - off] : 0;
        __syncthreads();
        sb[t] += add;
        __syncthreads();
    }
    blockbase[t] = sb[t] - v;
}

__global__ __launch_bounds__(256) void k_scan3(int* __restrict__ offs,
                                               const int* __restrict__ blockbase,
                                               int* __restrict__ cursor) {
    int t = threadIdx.x;
    int base = blockIdx.x * 1024 + t * 4;
    int add = blockbase[blockIdx.x];
    int4 o = *(int4*)(offs + base);
    o.x += add; o.y += add; o.z += add; o.w += add;
    *(int4*)(offs + base) = o;
    *(int4*)(cursor + base) = o;
}

__global__ __launch_bounds__(256) void k_place(const int* __restrict__ src,
                                               const int* __restrict__ dst,
                                               const float* __restrict__ ew,
                                               int* __restrict__ cursor,
                                               int* __restrict__ src_sorted,
                                               float* __restrict__ ew_sorted) {
    int e = blockIdx.x * 256 + threadIdx.x;
    int d = dst[e];
    int pos = atomicAdd(&cursor[d], 1);
    src_sorted[pos] = src[e];
    ew_sorted[pos] = ew[e];
}

// ---------- conv front-ends ----------
// y = x @ Wrel ; agg = x @ Wroot + b (seed)   x:[N,64]
__global__ __launch_bounds__(256) void k_gemm64(
    const float* __restrict__ x, const float* __restrict__ Wrel,
    const float* __restrict__ Wroot, const float* __restrict__ b,
    float* __restrict__ y, float* __restrict__ agg)
{
    __shared__ float wR[64*32];
    __shared__ float wT[64*32];
    __shared__ float bb[32];
    int t = threadIdx.x;
    for (int i = t; i < 64*32; i += 256) { wR[i] = Wrel[i]; wT[i] = Wroot[i]; }
    if (t < 32) bb[t] = b[t];
    __syncthreads();
    size_t node = (size_t)blockIdx.x * 256 + t;
    const float4* xr = (const float4*)(x + node*64);
    float aR[32], aT[32];
    #pragma unroll
    for (int j=0;j<32;++j){aR[j]=0.f;aT[j]=0.f;}
    for (int k4 = 0; k4 < 16; ++k4) {
        float4 xv = xr[k4];
        float xs[4] = {xv.x, xv.y, xv.z, xv.w};
        #pragma unroll
        for (int q=0;q<4;++q) {
            int k = k4*4+q;
            #pragma unroll
            for (int j=0;j<32;++j) {
                aR[j] = fmaf(xs[q], wR[k*32+j], aR[j]);
                aT[j] = fmaf(xs[q], wT[k*32+j], aT[j]);
            }
        }
    }
    float4* yr = (float4*)(y + node*32);
    float4* ar = (float4*)(agg + node*32);
    #pragma unroll
    for (int j4=0;j4<8;++j4) {
        yr[j4] = make_float4(aR[4*j4],aR[4*j4+1],aR[4*j4+2],aR[4*j4+3]);
        ar[j4] = make_float4(aT[4*j4]+bb[4*j4],aT[4*j4+1]+bb[4*j4+1],
                             aT[4*j4+2]+bb[4*j4+2],aT[4*j4+3]+bb[4*j4+3]);
    }
}

// In-place conv2 front-end: reads xagg row (=hp), writes y = hp@Wrel and
// overwrites xagg row with seed = hp@Wroot + b.
__global__ __launch_bounds__(256) void k_gemm32(
    float* __restrict__ xagg, const float* __restrict__ Wrel,
    const float* __restrict__ Wroot, const float* __restrict__ b,
    float* __restrict__ y)
{
    __shared__ float wR[32*32];
    __shared__ float wT[32*32];
    __shared__ float bb[32];
    int t = threadIdx.x;
    for (int i = t; i < 32*32; i += 256) { wR[i] = Wrel[i]; wT[i] = Wroot[i]; }
    if (t < 32) bb[t] = b[t];
    __syncthreads();
    size_t node = (size_t)blockIdx.x * 256 + t;
    float4* xr = (float4*)(xagg + node*32);
    float xs[32];
    #pragma unroll
    for (int k4=0;k4<8;++k4) {
        float4 xv = xr[k4];
        xs[4*k4]=xv.x; xs[4*k4+1]=xv.y; xs[4*k4+2]=xv.z; xs[4*k4+3]=xv.w;
    }
    float aR[32], aT[32];
    #pragma unroll
    for (int j=0;j<32;++j){aR[j]=0.f;aT[j]=0.f;}
    #pragma unroll
    for (int k=0;k<32;++k) {
        #pragma unroll
        for (int j=0;j<32;++j) {
            aR[j] = fmaf(xs[k], wR[k*32+j], aR[j]);
            aT[j] = fmaf(xs[k], wT[k*32+j], aT[j]);
        }
    }
    float4* yr = (float4*)(y + node*32);
    #pragma unroll
    for (int j4=0;j4<8;++j4) {
        yr[j4] = make_float4(aR[4*j4],aR[4*j4+1],aR[4*j4+2],aR[4*j4+3]);
        xr[j4] = make_float4(aT[4*j4]+bb[4*j4],aT[4*j4+1]+bb[4*j4+1],
                             aT[4*j4+2]+bb[4*j4+2],aT[4*j4+3]+bb[4*j4+3]);
    }
}

// ---------- fused gather + relu + score ----------
// 8 lanes per node. hagg holds seed on entry, h=relu(seed+sum) on exit.
// s = (h.pw)/||pw|| or -inf for masked-out nodes.
// conv2 note: masked src rows have y=0 (hp=0 @ Wrel), so no per-edge mask.
__global__ __launch_bounds__(256) void k_gather(
    const int* __restrict__ offsets, const int* __restrict__ counts,
    const int* __restrict__ src_sorted, const float* __restrict__ ew_sorted,
    const float* __restrict__ y, const float* __restrict__ pw,
    const int* __restrict__ mask, float* __restrict__ hagg,
    float* __restrict__ s)
{
    size_t tid = (size_t)blockIdx.x * 256 + threadIdx.x;
    int node = (int)(tid >> 3);
    int q = (int)(tid & 7);
    float4 wv = ((const float4*)pw)[q];
    float nn = wv.x*wv.x + wv.y*wv.y + wv.z*wv.z + wv.w*wv.w;
    nn += __shfl_xor(nn, 1); nn += __shfl_xor(nn, 2); nn += __shfl_xor(nn, 4);
    float nrm = sqrtf(nn);
    bool valid = mask ? (mask[node] != 0) : true;
    float4 acc = make_float4(0.f, 0.f, 0.f, 0.f);
    float4* hrow = (float4*)(hagg + (size_t)node * 32);
    if (valid) {
        acc = hrow[q];                       // seed = x@Wroot + b
        int beg = offsets[node];
        int end = beg + counts[node];
        for (int e = beg; e < end; ++e) {
            int sidx = src_sorted[e];        // broadcast across 8 lanes
            float w = ew_sorted[e];
            float4 v = *(const float4*)(y + (size_t)sidx * 32 + (size_t)q * 4);
            acc.x = fmaf(v.x, w, acc.x);
            acc.y = fmaf(v.y, w, acc.y);
            acc.z = fmaf(v.z, w, acc.z);
            acc.w = fmaf(v.w, w, acc.w);
        }
    }
    float4 hv;
    hv.x = fmaxf(acc.x, 0.f); hv.y = fmaxf(acc.y, 0.f);
    hv.z = fmaxf(acc.z, 0.f); hv.w = fmaxf(acc.w, 0.f);
    hrow[q] = hv;
    float dot = hv.x*wv.x + hv.y*wv.y + hv.z*wv.z + hv.w*wv.w;
    dot += __shfl_xor(dot, 1); dot += __shfl_xor(dot, 2); dot += __shfl_xor(dot, 4);
    if (q == 0) s[node] = valid ? (dot / nrm) : -INFINITY;
}

// ---------- pooling ----------
__global__ __launch_bounds__(256) void k_pool(
    const float* __restrict__ s, float* __restrict__ h,
    int write_hp, int* __restrict__ mask_out,
    float* __restrict__ xout, int ksel)
{
    __shared__ unsigned keys[NPG];
    __shared__ unsigned hist[256];
    __shared__ unsigned scanb[256];
    __shared__ unsigned char flag[NPG];
    __shared__ unsigned sh_bin, sh_krem;
    __shared__ float red[4*64];
    int t = threadIdx.x;
    int g = blockIdx.x;
    const float* sg = s + (size_t)g * NPG;
    for (int i = t; i < NPG; i += 256) {
        unsigned u = __float_as_uint(sg[i]);
        keys[i] = (u & 0x80000000u) ? ~u : (u | 0x80000000u);
    }
    __syncthreads();
    unsigned prefix = 0u;
    unsigned krem = (unsigned)ksel;
    for (int level = 0; level < 4; ++level) {
        int shift = 24 - 8*level;
        hist[t] = 0u;
        __syncthreads();
        unsigned pmask = level ? (0xFFFFFFFFu << (shift + 8)) : 0u;
        for (int i = t; i < NPG; i += 256) {
            unsigned key = keys[i];
            if ((key & pmask) == prefix)
                atomicAdd(&hist[(key >> shift) & 0xFFu], 1u);
        }
        __syncthreads();
        scanb[t] = hist[255 - t];
        __syncthreads();
        for (int off = 1; off < 256; off <<= 1) {
            unsigned add = (t >= off) ? scanb[t - off] : 0u;
            __syncthreads();
            scanb[t] += add;
            __syncthreads();
        }
        unsigned incl = scanb[t];
        unsigned excl = t ? scanb[t-1] : 0u;
        if (incl >= krem && excl < krem) {
            sh_bin = (unsigned)(255 - t);
            sh_krem = krem - excl;
        }
        __syncthreads();
        prefix |= (sh_bin << shift);
        krem = sh_krem;
        __syncthreads();
    }
    unsigned T = prefix;
    unsigned ties = krem;
    int base = t * 8;
    unsigned ceq = 0;
    #pragma unroll
    for (int i=0;i<8;++i) ceq += (keys[base+i] == T) ? 1u : 0u;
    scanb[t] = ceq;
    __syncthreads();
    for (int off = 1; off < 256; off <<= 1) {
        unsigned add = (t >= off) ? scanb[t - off] : 0u;
        __syncthreads();
        scanb[t] += add;
        __syncthreads();
    }
    unsigned run = scanb[t] - ceq;
    #pragma unroll
    for (int i=0;i<8;++i) {
        unsigned key = keys[base+i];
        unsigned char f;
        if (key > T) f = 1;
        else if (key == T) { f = (run < ties) ? 1 : 0; run++; }
        else f = 0;
        flag[base+i] = f;
    }
    __syncthreads();

    float mx[32], sm[32];
    #pragma unroll
    for (int j=0;j<32;++j){ mx[j]=-INFINITY; sm[j]=0.f; }
    float* hg = h + (size_t)g * NPG * 32;
    for (int i = t; i < NPG; i += 256) {
        bool sel = flag[i] != 0;
        float ts = sel ? tanhf(sg[i]) : 0.f;
        float4* hr = (float4*)(hg + (size_t)i*32);
        #pragma unroll
        for (int j4=0;j4<8;++j4) {
            float4 hv = hr[j4];
            float4 v = make_float4(hv.x*ts, hv.y*ts, hv.z*ts, hv.w*ts);
            if (write_hp) hr[j4] = v;
            if (sel) {
                mx[4*j4+0] = fmaxf(mx[4*j4+0], v.x); sm[4*j4+0] += v.x;
                mx[4*j4+1] = fmaxf(mx[4*j4+1], v.y); sm[4*j4+1] += v.y;
                mx[4*j4+2] = fmaxf(mx[4*j4+2], v.z); sm[4*j4+2] += v.z;
                mx[4*j4+3] = fmaxf(mx[4*j4+3], v.w); sm[4*j4+3] += v.w;
            }
        }
        if (mask_out) mask_out[(size_t)g*NPG + i] = sel ? 1 : 0;
    }
    #pragma unroll
    for (int j=0;j<32;++j) {
        for (int off=32; off; off>>=1) {
            mx[j] = fmaxf(mx[j], __shfl_xor(mx[j], off));
            sm[j] += __shfl_xor(sm[j], off);
        }
    }
    int wave = t >> 6, lane = t & 63;
    if (lane == 0) {
        #pragma unroll
        for (int j=0;j<32;++j) { red[wave*64 + j] = mx[j]; red[wave*64 + 32 + j] = sm[j]; }
    }
    __syncthreads();
    if (t < 32) {
        float m = red[t], ss = red[32 + t];
        #pragma unroll
        for (int w=1; w<4; ++w) { m = fmaxf(m, red[w*64 + t]); ss += red[w*64 + 32 + t]; }
        xout[(size_t)g*64 + t] = m;
        xout[(size_t)g*64 + 32 + t] = ss / (float)ksel;
    }
}

__global__ __launch_bounds__(128) void k_readout(
    const float* __restrict__ x1, const float* __restrict__ x2,
    const float* __restrict__ l1W, const float* __restrict__ l1b,
    const float* __restrict__ l2W, const float* __restrict__ l2b,
    const float* __restrict__ l3W, const float* __restrict__ l3b,
    float* __restrict__ out)
{
    int g = threadIdx.x;
    float z[64];
    #pragma unroll
    for (int i=0;i<64;++i) z[i] = x1[g*64+i] + x2[g*64+i];
    float a1[32];
    for (int j=0;j<32;++j) {
        float acc = l1b[j];
        #pragma unroll
        for (int i=0;i<64;++i) acc = fmaf(z[i], l1W[i*32+j], acc);
        a1[j] = fmaxf(acc, 0.f);
    }
    float a2[16];
    for (int j=0;j<16;++j) {
        float acc = l2b[j];
        #pragma unroll
        for (int i=0;i<32;++i) acc = fmaf(a1[i], l2W[i*16+j], acc);
        a2[j] = fmaxf(acc, 0.f);
    }
    float o0 = l3b[0], o1 = l3b[1];
    #pragma unroll
    for (int i=0;i<16;++i) { o0 = fmaf(a2[i], l3W[i*2+0], o0); o1 = fmaf(a2[i], l3W[i*2+1], o1); }
    float m = fmaxf(o0, o1);
    float lse = m + logf(expf(o0-m) + expf(o1-m));
    out[g*2+0] = o0 - lse;
    out[g*2+1] = o1 - lse;
}

extern "C" void kernel_launch(void* const* d_in, const int* in_sizes, int n_in,
                              void* d_out, int out_size, void* d_ws, size_t ws_size,
                              hipStream_t stream)
{
    const float* x      = (const float*)d_in[0];
    const int*   ei     = (const int*)d_in[1];   // int32 (JAX x64 disabled)
    const float* eattr  = (const float*)d_in[2];
    const float* W1rel  = (const float*)d_in[4];
    const float* b1     = (const float*)d_in[5];
    const float* W1root = (const float*)d_in[6];
    const float* p1w    = (const float*)d_in[7];
    const float* W2rel  = (const float*)d_in[8];
    const float* b2     = (const float*)d_in[9];
    const float* W2root = (const float*)d_in[10];
    const float* p2w    = (const float*)d_in[11];
    const float* l1W    = (const float*)d_in[12];
    const float* l1b    = (const float*)d_in[13];
    const float* l2W    = (const float*)d_in[14];
    const float* l2b    = (const float*)d_in[15];
    const float* l3W    = (const float*)d_in[16];
    const float* l3b    = (const float*)d_in[17];
    const int* srcp = ei;
    const int* dstp = ei + NEDGES;

    float* ws   = (float*)d_ws;
    float* y    = ws;                               // [NNODES,32]
    float* aggh = y    + (size_t)NNODES*32;         // [NNODES,32] seed/h/hp
    float* s1   = aggh + (size_t)NNODES*32;         // [NNODES]
    int*   mask = (int*)(s1 + NNODES);              // [NNODES]
    float* x1   = (float*)(mask + NNODES);          // [128,64]
    float* x2   = x1 + NGRAPH*64;                   // [128,64]
    int*   counts    = (int*)(x2 + NGRAPH*64);      // [NNODES]
    int*   offsets   = counts + NNODES;             // [NNODES]
    int*   cursor    = offsets + NNODES;            // [NNODES]
    int*   blocksum  = cursor + NNODES;             // [256]
    int*   blockbase = blocksum + 256;              // [256]
    int*   src_sorted= blockbase + 256;             // [NEDGES]
    float* ew_sorted = (float*)(src_sorted + NEDGES); // [NEDGES]
    float* out  = (float*)d_out;

    dim3 b256(256);
    // ---- CSR build (dst is layer-invariant; build once) ----
    k_zeroi<<<NNODES/1024, b256, 0, stream>>>((int4*)counts);
    k_hist<<<NEDGES/256, b256, 0, stream>>>(dstp, counts);
    k_scan1<<<256, b256, 0, stream>>>(counts, offsets, blocksum);
    k_scan2<<<1, b256, 0, stream>>>(blocksum, blockbase);
    k_scan3<<<256, b256, 0, stream>>>(offsets, blockbase, cursor);
    k_place<<<NEDGES/256, b256, 0, stream>>>(srcp, dstp, eattr, cursor,
                                             src_sorted, ew_sorted);
    // ---- conv1 (gather) + score ----
    k_gemm64<<<NNODES/256, b256, 0, stream>>>(x, W1rel, W1root, b1, y, aggh);
    k_gather<<<NNODES*8/256, b256, 0, stream>>>(offsets, counts, src_sorted,
                                                ew_sorted, y, p1w, nullptr,
                                                aggh, s1);
    // ---- pool1 (hp in place, mask, x1) ----
    k_pool<<<NGRAPH, b256, 0, stream>>>(s1, aggh, 1, mask, x1, KSEL1);
    // ---- conv2 (in-place seed) ----
    k_gemm32<<<NNODES/256, b256, 0, stream>>>(aggh, W2rel, W2root, b2, y);
    k_gather<<<NNODES*8/256, b256, 0, stream>>>(offsets, counts, src_sorted,
                                                ew_sorted, y, p2w, mask,
                                                aggh, s1);
    // ---- pool2 (x2 only) ----
    k_pool<<<NGRAPH, b256, 0, stream>>>(s1, aggh, 0, nullptr, x2, KSEL2);
    // ---- readout MLP ----
    k_readout<<<1, 128, 0, stream>>>(x1, x2, l1W, l1b, l2W, l2b, l3W, l3b, out);
}

// Round 4
// 372.004 us; speedup vs baseline: 4.4114x; 1.3644x over previous
//
#include <hip/hip_runtime.h>
#include <math.h>

#define NNODES (128*2048)
#define NEDGES (NNODES*8)
#define NPG 2048
#define EPG (NPG*8)
#define NGRAPH 128
#define KSEL1 1639
#define KSEL2 1312

// ---------- per-graph CSR build: hist + scan + place in one workgroup ----------
__global__ __launch_bounds__(256) void k_csr(
    const int* __restrict__ src, const int* __restrict__ dst,
    const float* __restrict__ ew, int* __restrict__ offsets,
    int* __restrict__ counts, int2* __restrict__ edge_sorted)
{
    __shared__ int cnt[NPG];       // 8 KB histogram
    __shared__ int curs[NPG];      // 8 KB cursor (starts at exclusive prefix)
    __shared__ int wsum[256];
    int t = threadIdx.x;
    int g = blockIdx.x;
    const int ebase = g * EPG;
    for (int i = t; i < NPG; i += 256) cnt[i] = 0;
    __syncthreads();
    for (int i = t; i < EPG; i += 256)
        atomicAdd(&cnt[dst[ebase + i] & (NPG-1)], 1);
    __syncthreads();
    // scan: thread t owns cnt[8t..8t+7]
    int base = t * 8;
    int loc[8]; int s0 = 0;
    #pragma unroll
    for (int i=0;i<8;++i){ loc[i]=cnt[base+i]; s0 += loc[i]; }
    wsum[t] = s0;
    __syncthreads();
    for (int off=1; off<256; off<<=1) {
        int add = (t>=off)?wsum[t-off]:0;
        __syncthreads();
        wsum[t]+=add;
        __syncthreads();
    }
    int run = wsum[t]-s0;
    #pragma unroll
    for (int i=0;i<8;++i){ curs[base+i]=run; run+=loc[i]; }
    __syncthreads();
    // export offsets/counts (coalesced) BEFORE cursors mutate
    for (int i = t; i < NPG; i += 256) {
        offsets[g*NPG + i] = ebase + curs[i];
        counts[g*NPG + i]  = cnt[i];
    }
    __syncthreads();
    // placement: random writes confined to this graph's 128 KB window
    for (int i = t; i < EPG; i += 256) {
        int d = dst[ebase + i] & (NPG-1);
        int pos = atomicAdd(&curs[d], 1);
        edge_sorted[ebase + pos] = make_int2(src[ebase+i], __float_as_int(ew[ebase+i]));
    }
}

// ---------- conv front-ends ----------
// y = x @ Wrel ; agg = x @ Wroot + b (seed)   x:[N,64]
__global__ __launch_bounds__(256) void k_gemm64(
    const float* __restrict__ x, const float* __restrict__ Wrel,
    const float* __restrict__ Wroot, const float* __restrict__ b,
    float* __restrict__ y, float* __restrict__ agg)
{
    __shared__ float wR[64*32];
    __shared__ float wT[64*32];
    __shared__ float bb[32];
    int t = threadIdx.x;
    for (int i = t; i < 64*32; i += 256) { wR[i] = Wrel[i]; wT[i] = Wroot[i]; }
    if (t < 32) bb[t] = b[t];
    __syncthreads();
    size_t node = (size_t)blockIdx.x * 256 + t;
    const float4* xr = (const float4*)(x + node*64);
    float aR[32], aT[32];
    #pragma unroll
    for (int j=0;j<32;++j){aR[j]=0.f;aT[j]=0.f;}
    for (int k4 = 0; k4 < 16; ++k4) {
        float4 xv = xr[k4];
        float xs[4] = {xv.x, xv.y, xv.z, xv.w};
        #pragma unroll
        for (int q=0;q<4;++q) {
            int k = k4*4+q;
            #pragma unroll
            for (int j=0;j<32;++j) {
                aR[j] = fmaf(xs[q], wR[k*32+j], aR[j]);
                aT[j] = fmaf(xs[q], wT[k*32+j], aT[j]);
            }
        }
    }
    float4* yr = (float4*)(y + node*32);
    float4* ar = (float4*)(agg + node*32);
    #pragma unroll
    for (int j4=0;j4<8;++j4) {
        yr[j4] = make_float4(aR[4*j4],aR[4*j4+1],aR[4*j4+2],aR[4*j4+3]);
        ar[j4] = make_float4(aT[4*j4]+bb[4*j4],aT[4*j4+1]+bb[4*j4+1],
                             aT[4*j4+2]+bb[4*j4+2],aT[4*j4+3]+bb[4*j4+3]);
    }
}

// In-place conv2 front-end: reads xagg row (=hp), writes y = hp@Wrel and
// overwrites xagg row with seed = hp@Wroot + b.
__global__ __launch_bounds__(256) void k_gemm32(
    float* __restrict__ xagg, const float* __restrict__ Wrel,
    const float* __restrict__ Wroot, const float* __restrict__ b,
    float* __restrict__ y)
{
    __shared__ float wR[32*32];
    __shared__ float wT[32*32];
    __shared__ float bb[32];
    int t = threadIdx.x;
    for (int i = t; i < 32*32; i += 256) { wR[i] = Wrel[i]; wT[i] = Wroot[i]; }
    if (t < 32) bb[t] = b[t];
    __syncthreads();
    size_t node = (size_t)blockIdx.x * 256 + t;
    float4* xr = (float4*)(xagg + node*32);
    float xs[32];
    #pragma unroll
    for (int k4=0;k4<8;++k4) {
        float4 xv = xr[k4];
        xs[4*k4]=xv.x; xs[4*k4+1]=xv.y; xs[4*k4+2]=xv.z; xs[4*k4+3]=xv.w;
    }
    float aR[32], aT[32];
    #pragma unroll
    for (int j=0;j<32;++j){aR[j]=0.f;aT[j]=0.f;}
    #pragma unroll
    for (int k=0;k<32;++k) {
        #pragma unroll
        for (int j=0;j<32;++j) {
            aR[j] = fmaf(xs[k], wR[k*32+j], aR[j]);
            aT[j] = fmaf(xs[k], wT[k*32+j], aT[j]);
        }
    }
    float4* yr = (float4*)(y + node*32);
    #pragma unroll
    for (int j4=0;j4<8;++j4) {
        yr[j4] = make_float4(aR[4*j4],aR[4*j4+1],aR[4*j4+2],aR[4*j4+3]);
        xr[j4] = make_float4(aT[4*j4]+bb[4*j4],aT[4*j4+1]+bb[4*j4+1],
                             aT[4*j4+2]+bb[4*j4+2],aT[4*j4+3]+bb[4*j4+3]);
    }
}

// ---------- fused gather + relu + score ----------
// 8 lanes per node. hagg holds seed on entry, h=relu(seed+sum) on exit.
// s = (h.pw)/||pw|| or -inf for masked-out nodes.
__global__ __launch_bounds__(256) void k_gather(
    const int* __restrict__ offsets, const int* __restrict__ counts,
    const int2* __restrict__ edge_sorted,
    const float* __restrict__ y, const float* __restrict__ pw,
    const int* __restrict__ mask, float* __restrict__ hagg,
    float* __restrict__ s)
{
    size_t tid = (size_t)blockIdx.x * 256 + threadIdx.x;
    int node = (int)(tid >> 3);
    int q = (int)(tid & 7);
    float4 wv = ((const float4*)pw)[q];
    float nn = wv.x*wv.x + wv.y*wv.y + wv.z*wv.z + wv.w*wv.w;
    nn += __shfl_xor(nn, 1); nn += __shfl_xor(nn, 2); nn += __shfl_xor(nn, 4);
    float nrm = sqrtf(nn);
    bool valid = mask ? (mask[node] != 0) : true;
    float4 acc = make_float4(0.f, 0.f, 0.f, 0.f);
    float4* hrow = (float4*)(hagg + (size_t)node * 32);
    if (valid) {
        acc = hrow[q];                       // seed = x@Wroot + b
        int beg = offsets[node];
        int end = beg + counts[node];
        for (int e = beg; e < end; ++e) {
            int2 ed = edge_sorted[e];        // broadcast across 8 lanes
            float w = __int_as_float(ed.y);
            float4 v = *(const float4*)(y + (size_t)ed.x * 32 + (size_t)q * 4);
            acc.x = fmaf(v.x, w, acc.x);
            acc.y = fmaf(v.y, w, acc.y);
            acc.z = fmaf(v.z, w, acc.z);
            acc.w = fmaf(v.w, w, acc.w);
        }
    }
    float4 hv;
    hv.x = fmaxf(acc.x, 0.f); hv.y = fmaxf(acc.y, 0.f);
    hv.z = fmaxf(acc.z, 0.f); hv.w = fmaxf(acc.w, 0.f);
    hrow[q] = hv;
    float dot = hv.x*wv.x + hv.y*wv.y + hv.z*wv.z + hv.w*wv.w;
    dot += __shfl_xor(dot, 1); dot += __shfl_xor(dot, 2); dot += __shfl_xor(dot, 4);
    if (q == 0) s[node] = valid ? (dot / nrm) : -INFINITY;
}

// ---------- pooling ----------
__global__ __launch_bounds__(256) void k_pool(
    const float* __restrict__ s, float* __restrict__ h,
    int write_hp, int* __restrict__ mask_out,
    float* __restrict__ xout, int ksel)
{
    __shared__ unsigned keys[NPG];
    __shared__ unsigned hist[256];
    __shared__ unsigned scanb[256];
    __shared__ unsigned char flag[NPG];
    __shared__ unsigned sh_bin, sh_krem;
    __shared__ float red[4*64];
    int t = threadIdx.x;
    int g = blockIdx.x;
    const float* sg = s + (size_t)g * NPG;
    for (int i = t; i < NPG; i += 256) {
        unsigned u = __float_as_uint(sg[i]);
        keys[i] = (u & 0x80000000u) ? ~u : (u | 0x80000000u);
    }
    __syncthreads();
    unsigned prefix = 0u;
    unsigned krem = (unsigned)ksel;
    for (int level = 0; level < 4; ++level) {
        int shift = 24 - 8*level;
        hist[t] = 0u;
        __syncthreads();
        unsigned pmask = level ? (0xFFFFFFFFu << (shift + 8)) : 0u;
        for (int i = t; i < NPG; i += 256) {
            unsigned key = keys[i];
            if ((key & pmask) == prefix)
                atomicAdd(&hist[(key >> shift) & 0xFFu], 1u);
        }
        __syncthreads();
        scanb[t] = hist[255 - t];
        __syncthreads();
        for (int off = 1; off < 256; off <<= 1) {
            unsigned add = (t >= off) ? scanb[t - off] : 0u;
            __syncthreads();
            scanb[t] += add;
            __syncthreads();
        }
        unsigned incl = scanb[t];
        unsigned excl = t ? scanb[t-1] : 0u;
        if (incl >= krem && excl < krem) {
            sh_bin = (unsigned)(255 - t);
            sh_krem = krem - excl;
        }
        __syncthreads();
        prefix |= (sh_bin << shift);
        krem = sh_krem;
        __syncthreads();
    }
    unsigned T = prefix;
    unsigned ties = krem;
    int base = t * 8;
    unsigned ceq = 0;
    #pragma unroll
    for (int i=0;i<8;++i) ceq += (keys[base+i] == T) ? 1u : 0u;
    scanb[t] = ceq;
    __syncthreads();
    for (int off = 1; off < 256; off <<= 1) {
        unsigned add = (t >= off) ? scanb[t - off] : 0u;
        __syncthreads();
        scanb[t] += add;
        __syncthreads();
    }
    unsigned run = scanb[t] - ceq;
    #pragma unroll
    for (int i=0;i<8;++i) {
        unsigned key = keys[base+i];
        unsigned char f;
        if (key > T) f = 1;
        else if (key == T) { f = (run < ties) ? 1 : 0; run++; }
        else f = 0;
        flag[base+i] = f;
    }
    __syncthreads();

    float mx[32], sm[32];
    #pragma unroll
    for (int j=0;j<32;++j){ mx[j]=-INFINITY; sm[j]=0.f; }
    float* hg = h + (size_t)g * NPG * 32;
    for (int i = t; i < NPG; i += 256) {
        bool sel = flag[i] != 0;
        float ts = sel ? tanhf(sg[i]) : 0.f;
        float4* hr = (float4*)(hg + (size_t)i*32);
        #pragma unroll
        for (int j4=0;j4<8;++j4) {
            float4 hv = hr[j4];
            float4 v = make_float4(hv.x*ts, hv.y*ts, hv.z*ts, hv.w*ts);
            if (write_hp) hr[j4] = v;
            if (sel) {
                mx[4*j4+0] = fmaxf(mx[4*j4+0], v.x); sm[4*j4+0] += v.x;
                mx[4*j4+1] = fmaxf(mx[4*j4+1], v.y); sm[4*j4+1] += v.y;
                mx[4*j4+2] = fmaxf(mx[4*j4+2], v.z); sm[4*j4+2] += v.z;
                mx[4*j4+3] = fmaxf(mx[4*j4+3], v.w); sm[4*j4+3] += v.w;
            }
        }
        if (mask_out) mask_out[(size_t)g*NPG + i] = sel ? 1 : 0;
    }
    #pragma unroll
    for (int j=0;j<32;++j) {
        for (int off=32; off; off>>=1) {
            mx[j] = fmaxf(mx[j], __shfl_xor(mx[j], off));
            sm[j] += __shfl_xor(sm[j], off);
        }
    }
    int wave = t >> 6, lane = t & 63;
    if (lane == 0) {
        #pragma unroll
        for (int j=0;j<32;++j) { red[wave*64 + j] = mx[j]; red[wave*64 + 32 + j] = sm[j]; }
    }
    __syncthreads();
    if (t < 32) {
        float m = red[t], ss = red[32 + t];
        #pragma unroll
        for (int w=1; w<4; ++w) { m = fmaxf(m, red[w*64 + t]); ss += red[w*64 + 32 + t]; }
        xout[(size_t)g*64 + t] = m;
        xout[(size_t)g*64 + 32 + t] = ss / (float)ksel;
    }
}

__global__ __launch_bounds__(128) void k_readout(
    const float* __restrict__ x1, const float* __restrict__ x2,
    const float* __restrict__ l1W, const float* __restrict__ l1b,
    const float* __restrict__ l2W, const float* __restrict__ l2b,
    const float* __restrict__ l3W, const float* __restrict__ l3b,
    float* __restrict__ out)
{
    int g = threadIdx.x;
    float z[64];
    #pragma unroll
    for (int i=0;i<64;++i) z[i] = x1[g*64+i] + x2[g*64+i];
    float a1[32];
    for (int j=0;j<32;++j) {
        float acc = l1b[j];
        #pragma unroll
        for (int i=0;i<64;++i) acc = fmaf(z[i], l1W[i*32+j], acc);
        a1[j] = fmaxf(acc, 0.f);
    }
    float a2[16];
    for (int j=0;j<16;++j) {
        float acc = l2b[j];
        #pragma unroll
        for (int i=0;i<32;++i) acc = fmaf(a1[i], l2W[i*16+j], acc);
        a2[j] = fmaxf(acc, 0.f);
    }
    float o0 = l3b[0], o1 = l3b[1];
    #pragma unroll
    for (int i=0;i<16;++i) { o0 = fmaf(a2[i], l3W[i*2+0], o0); o1 = fmaf(a2[i], l3W[i*2+1], o1); }
    float m = fmaxf(o0, o1);
    float lse = m + logf(expf(o0-m) + expf(o1-m));
    out[g*2+0] = o0 - lse;
    out[g*2+1] = o1 - lse;
}

extern "C" void kernel_launch(void* const* d_in, const int* in_sizes, int n_in,
                              void* d_out, int out_size, void* d_ws, size_t ws_size,
                              hipStream_t stream)
{
    const float* x      = (const float*)d_in[0];
    const int*   ei     = (const int*)d_in[1];   // int32 (JAX x64 disabled)
    const float* eattr  = (const float*)d_in[2];
    const float* W1rel  = (const float*)d_in[4];
    const float* b1     = (const float*)d_in[5];
    const float* W1root = (const float*)d_in[6];
    const float* p1w    = (const float*)d_in[7];
    const float* W2rel  = (const float*)d_in[8];
    const float* b2     = (const float*)d_in[9];
    const float* W2root = (const float*)d_in[10];
    const float* p2w    = (const float*)d_in[11];
    const float* l1W    = (const float*)d_in[12];
    const float* l1b    = (const float*)d_in[13];
    const float* l2W    = (const float*)d_in[14];
    const float* l2b    = (const float*)d_in[15];
    const float* l3W    = (const float*)d_in[16];
    const float* l3b    = (const float*)d_in[17];
    const int* srcp = ei;
    const int* dstp = ei + NEDGES;

    float* ws   = (float*)d_ws;
    float* y    = ws;                                 // [NNODES,32]
    float* aggh = y    + (size_t)NNODES*32;           // [NNODES,32] seed/h/hp
    float* s1   = aggh + (size_t)NNODES*32;           // [NNODES]
    int*   mask = (int*)(s1 + NNODES);                // [NNODES]
    float* x1   = (float*)(mask + NNODES);            // [128,64]
    float* x2   = x1 + NGRAPH*64;                     // [128,64]
    int*   counts    = (int*)(x2 + NGRAPH*64);        // [NNODES]
    int*   offsets   = counts + NNODES;               // [NNODES]
    int2*  edge_sorted = (int2*)(offsets + NNODES);   // [NEDGES] (src, ew)
    float* out  = (float*)d_out;

    dim3 b256(256);
    // ---- CSR build: one workgroup per graph ----
    k_csr<<<NGRAPH, b256, 0, stream>>>(srcp, dstp, eattr, offsets, counts,
                                       edge_sorted);
    // ---- conv1 (gather) + score ----
    k_gemm64<<<NNODES/256, b256, 0, stream>>>(x, W1rel, W1root, b1, y, aggh);
    k_gather<<<NNODES*8/256, b256, 0, stream>>>(offsets, counts, edge_sorted,
                                                y, p1w, nullptr, aggh, s1);
    // ---- pool1 (hp in place, mask, x1) ----
    k_pool<<<NGRAPH, b256, 0, stream>>>(s1, aggh, 1, mask, x1, KSEL1);
    // ---- conv2 (in-place seed) ----
    k_gemm32<<<NNODES/256, b256, 0, stream>>>(aggh, W2rel, W2root, b2, y);
    k_gather<<<NNODES*8/256, b256, 0, stream>>>(offsets, counts, edge_sorted,
                                                y, p2w, mask, aggh, s1);
    // ---- pool2 (x2 only) ----
    k_pool<<<NGRAPH, b256, 0, stream>>>(s1, aggh, 0, nullptr, x2, KSEL2);
    // ---- readout MLP ----
    k_readout<<<1, 128, 0, stream>>>(x1, x2, l1W, l1b, l2W, l2b, l3W, l3b, out);
}

// Round 5
// 351.549 us; speedup vs baseline: 4.6681x; 1.0582x over previous
//
#include <hip/hip_runtime.h>
#include <math.h>

#define NNODES (128*2048)
#define NEDGES (NNODES*8)
#define NPG 2048
#define EPG (NPG*8)
#define NGRAPH 128
#define KSEL1 1639
#define KSEL2 1312

// ---------- per-graph CSR build: hist + scan + place, one 1024-thread WG ----------
__global__ __launch_bounds__(1024) void k_csr(
    const int* __restrict__ src, const int* __restrict__ dst,
    const float* __restrict__ ew, int* __restrict__ offsets,
    int* __restrict__ counts, int2* __restrict__ edge_sorted)
{
    __shared__ int cnt[NPG];       // 8 KB histogram
    __shared__ int curs[NPG];      // 8 KB cursor (starts at exclusive prefix)
    __shared__ int wsum[1024];
    int t = threadIdx.x;
    int g = blockIdx.x;
    const int ebase = g * EPG;
    for (int i = t; i < NPG; i += 1024) cnt[i] = 0;
    __syncthreads();
    for (int i = t; i < EPG; i += 1024)
        atomicAdd(&cnt[dst[ebase + i] & (NPG-1)], 1);
    __syncthreads();
    // scan: thread t owns cnt[2t..2t+1]
    int base = t * 2;
    int l0 = cnt[base], l1 = cnt[base+1];
    int s0 = l0 + l1;
    wsum[t] = s0;
    __syncthreads();
    for (int off=1; off<1024; off<<=1) {
        int add = (t>=off)?wsum[t-off]:0;
        __syncthreads();
        wsum[t]+=add;
        __syncthreads();
    }
    int run = wsum[t]-s0;
    curs[base] = run; curs[base+1] = run + l0;
    __syncthreads();
    // export offsets/counts (coalesced) BEFORE cursors mutate
    for (int i = t; i < NPG; i += 1024) {
        offsets[g*NPG + i] = ebase + curs[i];
        counts[g*NPG + i]  = cnt[i];
    }
    __syncthreads();
    // placement: random writes confined to this graph's 128 KB window
    for (int i = t; i < EPG; i += 1024) {
        int d = dst[ebase + i] & (NPG-1);
        int pos = atomicAdd(&curs[d], 1);
        edge_sorted[ebase + pos] = make_int2(src[ebase+i], __float_as_int(ew[ebase+i]));
    }
}

// ---------- conv front-ends ----------
// y = x @ Wrel ; agg = x @ Wroot + b (seed)   x:[N,64]
__global__ __launch_bounds__(256) void k_gemm64(
    const float* __restrict__ x, const float* __restrict__ Wrel,
    const float* __restrict__ Wroot, const float* __restrict__ b,
    float* __restrict__ y, float* __restrict__ agg)
{
    __shared__ float wR[64*32];
    __shared__ float wT[64*32];
    __shared__ float bb[32];
    int t = threadIdx.x;
    for (int i = t; i < 64*32; i += 256) { wR[i] = Wrel[i]; wT[i] = Wroot[i]; }
    if (t < 32) bb[t] = b[t];
    __syncthreads();
    size_t node = (size_t)blockIdx.x * 256 + t;
    const float4* xr = (const float4*)(x + node*64);
    float aR[32], aT[32];
    #pragma unroll
    for (int j=0;j<32;++j){aR[j]=0.f;aT[j]=0.f;}
    for (int k4 = 0; k4 < 16; ++k4) {
        float4 xv = xr[k4];
        float xs[4] = {xv.x, xv.y, xv.z, xv.w};
        #pragma unroll
        for (int q=0;q<4;++q) {
            int k = k4*4+q;
            #pragma unroll
            for (int j=0;j<32;++j) {
                aR[j] = fmaf(xs[q], wR[k*32+j], aR[j]);
                aT[j] = fmaf(xs[q], wT[k*32+j], aT[j]);
            }
        }
    }
    float4* yr = (float4*)(y + node*32);
    float4* ar = (float4*)(agg + node*32);
    #pragma unroll
    for (int j4=0;j4<8;++j4) {
        yr[j4] = make_float4(aR[4*j4],aR[4*j4+1],aR[4*j4+2],aR[4*j4+3]);
        ar[j4] = make_float4(aT[4*j4]+bb[4*j4],aT[4*j4+1]+bb[4*j4+1],
                             aT[4*j4+2]+bb[4*j4+2],aT[4*j4+3]+bb[4*j4+3]);
    }
}

// conv2 front-end: reads h row, scales by ts[node] (=tanh(score) or 0),
// writes y = (h*ts)@Wrel and overwrites h row with seed = (h*ts)@Wroot + b.
__global__ __launch_bounds__(256) void k_gemm32(
    float* __restrict__ xagg, const float* __restrict__ ts,
    const float* __restrict__ Wrel, const float* __restrict__ Wroot,
    const float* __restrict__ b, float* __restrict__ y)
{
    __shared__ float wR[32*32];
    __shared__ float wT[32*32];
    __shared__ float bb[32];
    int t = threadIdx.x;
    for (int i = t; i < 32*32; i += 256) { wR[i] = Wrel[i]; wT[i] = Wroot[i]; }
    if (t < 32) bb[t] = b[t];
    __syncthreads();
    size_t node = (size_t)blockIdx.x * 256 + t;
    float sc = ts[node];
    float4* xr = (float4*)(xagg + node*32);
    float xs[32];
    #pragma unroll
    for (int k4=0;k4<8;++k4) {
        float4 xv = xr[k4];
        xs[4*k4]=xv.x*sc; xs[4*k4+1]=xv.y*sc; xs[4*k4+2]=xv.z*sc; xs[4*k4+3]=xv.w*sc;
    }
    float aR[32], aT[32];
    #pragma unroll
    for (int j=0;j<32;++j){aR[j]=0.f;aT[j]=0.f;}
    #pragma unroll
    for (int k=0;k<32;++k) {
        #pragma unroll
        for (int j=0;j<32;++j) {
            aR[j] = fmaf(xs[k], wR[k*32+j], aR[j]);
            aT[j] = fmaf(xs[k], wT[k*32+j], aT[j]);
        }
    }
    float4* yr = (float4*)(y + node*32);
    #pragma unroll
    for (int j4=0;j4<8;++j4) {
        yr[j4] = make_float4(aR[4*j4],aR[4*j4+1],aR[4*j4+2],aR[4*j4+3]);
        xr[j4] = make_float4(aT[4*j4]+bb[4*j4],aT[4*j4+1]+bb[4*j4+1],
                             aT[4*j4+2]+bb[4*j4+2],aT[4*j4+3]+bb[4*j4+3]);
    }
}

// ---------- fused gather + relu + score ----------
// 8 lanes per node. hagg holds seed on entry, h=relu(seed+sum) on exit.
// s = (h.pw)/||pw|| or -inf for masked-out nodes.
__global__ __launch_bounds__(256) void k_gather(
    const int* __restrict__ offsets, const int* __restrict__ counts,
    const int2* __restrict__ edge_sorted,
    const float* __restrict__ y, const float* __restrict__ pw,
    const int* __restrict__ mask, float* __restrict__ hagg,
    float* __restrict__ s)
{
    size_t tid = (size_t)blockIdx.x * 256 + threadIdx.x;
    int node = (int)(tid >> 3);
    int q = (int)(tid & 7);
    float4 wv = ((const float4*)pw)[q];
    float nn = wv.x*wv.x + wv.y*wv.y + wv.z*wv.z + wv.w*wv.w;
    nn += __shfl_xor(nn, 1); nn += __shfl_xor(nn, 2); nn += __shfl_xor(nn, 4);
    float nrm = sqrtf(nn);
    bool valid = mask ? (mask[node] != 0) : true;
    float4 acc = make_float4(0.f, 0.f, 0.f, 0.f);
    float4* hrow = (float4*)(hagg + (size_t)node * 32);
    if (valid) {
        acc = hrow[q];                       // seed = x@Wroot + b
        int beg = offsets[node];
        int end = beg + counts[node];
        for (int e = beg; e < end; ++e) {
            int2 ed = edge_sorted[e];        // broadcast across 8 lanes
            float w = __int_as_float(ed.y);
            float4 v = *(const float4*)(y + (size_t)ed.x * 32 + (size_t)q * 4);
            acc.x = fmaf(v.x, w, acc.x);
            acc.y = fmaf(v.y, w, acc.y);
            acc.z = fmaf(v.z, w, acc.z);
            acc.w = fmaf(v.w, w, acc.w);
        }
    }
    float4 hv;
    hv.x = fmaxf(acc.x, 0.f); hv.y = fmaxf(acc.y, 0.f);
    hv.z = fmaxf(acc.z, 0.f); hv.w = fmaxf(acc.w, 0.f);
    hrow[q] = hv;
    float dot = hv.x*wv.x + hv.y*wv.y + hv.z*wv.z + hv.w*wv.w;
    dot += __shfl_xor(dot, 1); dot += __shfl_xor(dot, 2); dot += __shfl_xor(dot, 4);
    if (q == 0) s[node] = valid ? (dot / nrm) : -INFINITY;
}

// ---------- pooling ----------
// Exact top-ksel per graph (radix select, index-stable ties).
// If ts_out: write ts=tanh(s) (0 if unselected) per node — h is NOT modified.
// xout[g] = concat(max over selected of h*ts, sum/ksel of h*ts)
__global__ __launch_bounds__(256) void k_pool(
    const float* __restrict__ s, const float* __restrict__ h,
    float* __restrict__ ts_out, int* __restrict__ mask_out,
    float* __restrict__ xout, int ksel)
{
    __shared__ unsigned keys[NPG];
    __shared__ unsigned hist[256];
    __shared__ unsigned scanb[256];
    __shared__ unsigned char flag[NPG];
    __shared__ unsigned sh_bin, sh_krem;
    __shared__ float red[4*64];
    int t = threadIdx.x;
    int g = blockIdx.x;
    const float* sg = s + (size_t)g * NPG;
    for (int i = t; i < NPG; i += 256) {
        unsigned u = __float_as_uint(sg[i]);
        keys[i] = (u & 0x80000000u) ? ~u : (u | 0x80000000u);
    }
    __syncthreads();
    unsigned prefix = 0u;
    unsigned krem = (unsigned)ksel;
    for (int level = 0; level < 4; ++level) {
        int shift = 24 - 8*level;
        hist[t] = 0u;
        __syncthreads();
        unsigned pmask = level ? (0xFFFFFFFFu << (shift + 8)) : 0u;
        for (int i = t; i < NPG; i += 256) {
            unsigned key = keys[i];
            if ((key & pmask) == prefix)
                atomicAdd(&hist[(key >> shift) & 0xFFu], 1u);
        }
        __syncthreads();
        scanb[t] = hist[255 - t];
        __syncthreads();
        for (int off = 1; off < 256; off <<= 1) {
            unsigned add = (t >= off) ? scanb[t - off] : 0u;
            __syncthreads();
            scanb[t] += add;
            __syncthreads();
        }
        unsigned incl = scanb[t];
        unsigned excl = t ? scanb[t-1] : 0u;
        if (incl >= krem && excl < krem) {
            sh_bin = (unsigned)(255 - t);
            sh_krem = krem - excl;
        }
        __syncthreads();
        prefix |= (sh_bin << shift);
        krem = sh_krem;
        __syncthreads();
    }
    unsigned T = prefix;
    unsigned ties = krem;
    int base = t * 8;
    unsigned ceq = 0;
    #pragma unroll
    for (int i=0;i<8;++i) ceq += (keys[base+i] == T) ? 1u : 0u;
    scanb[t] = ceq;
    __syncthreads();
    for (int off = 1; off < 256; off <<= 1) {
        unsigned add = (t >= off) ? scanb[t - off] : 0u;
        __syncthreads();
        scanb[t] += add;
        __syncthreads();
    }
    unsigned run = scanb[t] - ceq;
    #pragma unroll
    for (int i=0;i<8;++i) {
        unsigned key = keys[base+i];
        unsigned char f;
        if (key > T) f = 1;
        else if (key == T) { f = (run < ties) ? 1 : 0; run++; }
        else f = 0;
        flag[base+i] = f;
    }
    __syncthreads();

    float mx[32], sm[32];
    #pragma unroll
    for (int j=0;j<32;++j){ mx[j]=-INFINITY; sm[j]=0.f; }
    const float* hg = h + (size_t)g * NPG * 32;
    for (int i = t; i < NPG; i += 256) {
        bool sel = flag[i] != 0;
        float ts = sel ? tanhf(sg[i]) : 0.f;
        const float4* hr = (const float4*)(hg + (size_t)i*32);
        #pragma unroll
        for (int j4=0;j4<8;++j4) {
            float4 hv = hr[j4];
            float4 v = make_float4(hv.x*ts, hv.y*ts, hv.z*ts, hv.w*ts);
            if (sel) {
                mx[4*j4+0] = fmaxf(mx[4*j4+0], v.x); sm[4*j4+0] += v.x;
                mx[4*j4+1] = fmaxf(mx[4*j4+1], v.y); sm[4*j4+1] += v.y;
                mx[4*j4+2] = fmaxf(mx[4*j4+2], v.z); sm[4*j4+2] += v.z;
                mx[4*j4+3] = fmaxf(mx[4*j4+3], v.w); sm[4*j4+3] += v.w;
            }
        }
        if (ts_out) ts_out[(size_t)g*NPG + i] = ts;
        if (mask_out) mask_out[(size_t)g*NPG + i] = sel ? 1 : 0;
    }
    #pragma unroll
    for (int j=0;j<32;++j) {
        for (int off=32; off; off>>=1) {
            mx[j] = fmaxf(mx[j], __shfl_xor(mx[j], off));
            sm[j] += __shfl_xor(sm[j], off);
        }
    }
    int wave = t >> 6, lane = t & 63;
    if (lane == 0) {
        #pragma unroll
        for (int j=0;j<32;++j) { red[wave*64 + j] = mx[j]; red[wave*64 + 32 + j] = sm[j]; }
    }
    __syncthreads();
    if (t < 32) {
        float m = red[t], ss = red[32 + t];
        #pragma unroll
        for (int w=1; w<4; ++w) { m = fmaxf(m, red[w*64 + t]); ss += red[w*64 + 32 + t]; }
        xout[(size_t)g*64 + t] = m;
        xout[(size_t)g*64 + 32 + t] = ss / (float)ksel;
    }
}

__global__ __launch_bounds__(128) void k_readout(
    const float* __restrict__ x1, const float* __restrict__ x2,
    const float* __restrict__ l1W, const float* __restrict__ l1b,
    const float* __restrict__ l2W, const float* __restrict__ l2b,
    const float* __restrict__ l3W, const float* __restrict__ l3b,
    float* __restrict__ out)
{
    int g = threadIdx.x;
    float z[64];
    #pragma unroll
    for (int i=0;i<64;++i) z[i] = x1[g*64+i] + x2[g*64+i];
    float a1[32];
    for (int j=0;j<32;++j) {
        float acc = l1b[j];
        #pragma unroll
        for (int i=0;i<64;++i) acc = fmaf(z[i], l1W[i*32+j], acc);
        a1[j] = fmaxf(acc, 0.f);
    }
    float a2[16];
    for (int j=0;j<16;++j) {
        float acc = l2b[j];
        #pragma unroll
        for (int i=0;i<32;++i) acc = fmaf(a1[i], l2W[i*16+j], acc);
        a2[j] = fmaxf(acc, 0.f);
    }
    float o0 = l3b[0], o1 = l3b[1];
    #pragma unroll
    for (int i=0;i<16;++i) { o0 = fmaf(a2[i], l3W[i*2+0], o0); o1 = fmaf(a2[i], l3W[i*2+1], o1); }
    float m = fmaxf(o0, o1);
    float lse = m + logf(expf(o0-m) + expf(o1-m));
    out[g*2+0] = o0 - lse;
    out[g*2+1] = o1 - lse;
}

extern "C" void kernel_launch(void* const* d_in, const int* in_sizes, int n_in,
                              void* d_out, int out_size, void* d_ws, size_t ws_size,
                              hipStream_t stream)
{
    const float* x      = (const float*)d_in[0];
    const int*   ei     = (const int*)d_in[1];   // int32 (JAX x64 disabled)
    const float* eattr  = (const float*)d_in[2];
    const float* W1rel  = (const float*)d_in[4];
    const float* b1     = (const float*)d_in[5];
    const float* W1root = (const float*)d_in[6];
    const float* p1w    = (const float*)d_in[7];
    const float* W2rel  = (const float*)d_in[8];
    const float* b2     = (const float*)d_in[9];
    const float* W2root = (const float*)d_in[10];
    const float* p2w    = (const float*)d_in[11];
    const float* l1W    = (const float*)d_in[12];
    const float* l1b    = (const float*)d_in[13];
    const float* l2W    = (const float*)d_in[14];
    const float* l2b    = (const float*)d_in[15];
    const float* l3W    = (const float*)d_in[16];
    const float* l3b    = (const float*)d_in[17];
    const int* srcp = ei;
    const int* dstp = ei + NEDGES;

    float* ws   = (float*)d_ws;
    float* y    = ws;                                 // [NNODES,32]
    float* aggh = y    + (size_t)NNODES*32;           // [NNODES,32] seed/h
    float* s1   = aggh + (size_t)NNODES*32;           // [NNODES]
    float* ts   = s1 + NNODES;                        // [NNODES]
    int*   mask = (int*)(ts + NNODES);                // [NNODES]
    float* x1   = (float*)(mask + NNODES);            // [128,64]
    float* x2   = x1 + NGRAPH*64;                     // [128,64]
    int*   counts    = (int*)(x2 + NGRAPH*64);        // [NNODES]
    int*   offsets   = counts + NNODES;               // [NNODES]
    int2*  edge_sorted = (int2*)(offsets + NNODES);   // [NEDGES] (src, ew)
    float* out  = (float*)d_out;

    dim3 b256(256);
    // ---- CSR build: one 1024-thread workgroup per graph ----
    k_csr<<<NGRAPH, dim3(1024), 0, stream>>>(srcp, dstp, eattr, offsets, counts,
                                             edge_sorted);
    // ---- conv1 (gather) + score ----
    k_gemm64<<<NNODES/256, b256, 0, stream>>>(x, W1rel, W1root, b1, y, aggh);
    k_gather<<<NNODES*8/256, b256, 0, stream>>>(offsets, counts, edge_sorted,
                                                y, p1w, nullptr, aggh, s1);
    // ---- pool1 (ts + mask + x1; h untouched) ----
    k_pool<<<NGRAPH, b256, 0, stream>>>(s1, aggh, ts, mask, x1, KSEL1);
    // ---- conv2 (scale-by-ts fused into GEMM; in-place seed) ----
    k_gemm32<<<NNODES/256, b256, 0, stream>>>(aggh, ts, W2rel, W2root, b2, y);
    k_gather<<<NNODES*8/256, b256, 0, stream>>>(offsets, counts, edge_sorted,
                                                y, p2w, mask, aggh, s1);
    // ---- pool2 (x2 only) ----
    k_pool<<<NGRAPH, b256, 0, stream>>>(s1, aggh, nullptr, nullptr, x2, KSEL2);
    // ---- readout MLP ----
    k_readout<<<1, 128, 0, stream>>>(x1, x2, l1W, l1b, l2W, l2b, l3W, l3b, out);
}